// Round 21
// baseline (128.985 us; speedup 1.0000x reference)
//
#include <hip/hip_runtime.h>
#include <hip/hip_bf16.h>
#include <stdint.h>

#define N_NODES 100000
#define N_EDGES 3200000
#define F_IN 256
#define HID 16
#define NCLS 7

#define NBUCK 391        // ceil(100000 / 256) buckets of 256 nodes (dst >> 8)
#define BCAP 9216        // capacity per bucket (avg 8184 -> ample headroom)
#define EPB 4096         // edges per bucket-block (8 per thread @512)
#define NBLK ((N_EDGES + EPB - 1) / EPB)              // 782

using frag8 = __attribute__((ext_vector_type(8))) short;
using f32x4 = __attribute__((ext_vector_type(4))) float;

__device__ inline short f32_to_bf16_rn(float f) {
    uint32_t u = __float_as_uint(f);
    uint32_t r = (u + 0x7FFF + ((u >> 16) & 1)) >> 16;
    return (short)r;
}
__device__ inline float bf16_to_f32(short s) {
    return __uint_as_float(((uint32_t)(uint16_t)s) << 16);
}
__device__ inline short f32_bf16_native(float f) {
    __hip_bfloat16 h = __float2bfloat16(f);
    union { __hip_bfloat16 b; unsigned short u; } cv;
    cv.b = h;
    return (short)cv.u;
}

// ---------------- K1: ROLE-INTERLEAVED bucket ∥ GEMM blocks (r20 form) -----
__global__ __launch_bounds__(512) void k1_kernel(const void* edge_raw,
                                                 int* gcount, uint32_t* temp,
                                                 const float* __restrict__ x,
                                                 const float* __restrict__ W1,
                                                 float* __restrict__ y1f) {
    __shared__ __align__(16) char smem[32768];
    int t = threadIdx.x;
    int lane = t & 63;
    int wvid = t >> 6;
    int role = blockIdx.x & 1;
    int bid = blockIdx.x >> 1;
    if (role == 0) {
        uint32_t* buf2      = (uint32_t*)smem;            // 16384 B
        uint16_t* bucket_of = (uint16_t*)(smem + 16384);  //  8192 B
        int* cnt   = (int*)(smem + 24576);                //  1564 B
        int* lofs  = (int*)(smem + 26140);                //  1568 B
        int* gbase = (int*)(smem + 27708);                //  1564 B
        int* wsum  = (int*)(smem + 29272);                //    32 B
        int* s_is32 = (int*)(smem + 29304);               //     4 B
        if (t == 0) *s_is32 = 0;
        if (t < NBUCK) cnt[t] = 0;
        __syncthreads();
        uint32_t probe = ((const uint32_t*)edge_raw)[2 * t + 1];
        if (probe) atomicOr(s_is32, 1);
        __syncthreads();
        int is64 = (*s_is32 == 0);
        int e0 = bid * EPB;
        int total = min(EPB, N_EDGES - e0);
        int sv[8], dvv[8];
        if (is64) {
            const long long* pS = (const long long*)edge_raw + e0;
            const long long* pD = (const long long*)edge_raw + N_EDGES + e0;
            ulonglong2 sp[4], dp[4];
#pragma unroll
            for (int k = 0; k < 4; ++k) {
                int be = e0 + k * 1024 + 2 * t;
                if (be + 1 < N_EDGES) {
                    sp[k] = ((const ulonglong2*)(pS + k * 1024))[t];
                    dp[k] = ((const ulonglong2*)(pD + k * 1024))[t];
                } else {
                    sp[k].x = (be < N_EDGES) ? (unsigned long long)pS[k * 1024 + 2 * t] : ~0ull;
                    sp[k].y = ~0ull;
                    dp[k].x = (be < N_EDGES) ? (unsigned long long)pD[k * 1024 + 2 * t] : ~0ull;
                    dp[k].y = ~0ull;
                }
            }
#pragma unroll
            for (int k = 0; k < 4; ++k) {
                int be = e0 + k * 1024 + 2 * t;
                sv[2 * k]      = (be < N_EDGES) ? (int)sp[k].x : -1;
                dvv[2 * k]     = (be < N_EDGES) ? (int)dp[k].x : -1;
                sv[2 * k + 1]  = (be + 1 < N_EDGES) ? (int)sp[k].y : -1;
                dvv[2 * k + 1] = (be + 1 < N_EDGES) ? (int)dp[k].y : -1;
            }
        } else {
            const int* pS = (const int*)edge_raw + e0;
            const int* pD = (const int*)edge_raw + N_EDGES + e0;
            int4 sq[2], dq[2];
#pragma unroll
            for (int k = 0; k < 2; ++k) {
                int be = e0 + k * 2048 + 4 * t;
                if (be + 3 < N_EDGES) {
                    sq[k] = ((const int4*)(pS + k * 2048))[t];
                    dq[k] = ((const int4*)(pD + k * 2048))[t];
                } else {
                    int* s4 = (int*)&sq[k]; int* d4 = (int*)&dq[k];
#pragma unroll
                    for (int j = 0; j < 4; ++j) {
                        int e = be + j;
                        s4[j] = (e < N_EDGES) ? pS[k * 2048 + 4 * t + j] : -1;
                        d4[j] = (e < N_EDGES) ? pD[k * 2048 + 4 * t + j] : -1;
                    }
                }
            }
#pragma unroll
            for (int k = 0; k < 2; ++k) {
                int be = e0 + k * 2048 + 4 * t;
                const int* s4 = (const int*)&sq[k];
                const int* d4 = (const int*)&dq[k];
#pragma unroll
                for (int j = 0; j < 4; ++j) {
                    int slot = 4 * k + j;
                    int ok = (be + j < N_EDGES);
                    sv[slot] = ok ? s4[j] : -1;
                    dvv[slot] = ok ? d4[j] : -1;
                }
            }
        }
        uint32_t val[8];
        int bk[8], rk[8];
#pragma unroll
        for (int k = 0; k < 8; ++k) {
            if (dvv[k] >= 0) {
                int b = dvv[k] >> 8;
                val[k] = ((uint32_t)sv[k] << 8) | (uint32_t)(dvv[k] & 255);
                bk[k] = b;
                rk[k] = atomicAdd(&cnt[b], 1);
            } else {
                bk[k] = -1;
            }
        }
        __syncthreads();
        int cv = (t < NBUCK) ? cnt[t] : 0;
        int v = cv;
#pragma unroll
        for (int d = 1; d < 64; d <<= 1) {
            int up = __shfl_up(v, d);
            if (lane >= d) v += up;
        }
        if (lane == 63) wsum[wvid] = v;
        __syncthreads();
        int pre = 0;
#pragma unroll
        for (int w = 0; w < 8; ++w) pre += (w < wvid) ? wsum[w] : 0;
        if (t < NBUCK) lofs[t] = pre + v - cv;
        __syncthreads();
#pragma unroll
        for (int k = 0; k < 8; ++k) {
            if (bk[k] >= 0) {
                int p = lofs[bk[k]] + rk[k];
                buf2[p] = val[k];
                bucket_of[p] = (uint16_t)bk[k];
            }
        }
        if (t < NBUCK) {
            int c = cnt[t];
            gbase[t] = c ? atomicAdd(&gcount[t], c) : 0;
        }
        __syncthreads();
        for (int i = t; i < total; i += 512) {
            int b = bucket_of[i];
            int pos = gbase[b] + (i - lofs[b]);
            if (pos < BCAP) temp[(size_t)b * BCAP + pos] = buf2[i];
        }
    } else {
        short* whl = (short*)smem;            // 8192 B
        short* wll = (short*)(smem + 8192);   // 8192 B
#pragma unroll
        for (int j = 0; j < 8; ++j) {
            int wdx = t * 8 + j;
            float wvv = W1[wdx];
            short h = f32_to_bf16_rn(wvv);
            short lo = f32_to_bf16_rn(wvv - bf16_to_f32(h));
            int k = wdx >> 4, c = wdx & 15;
            int s = k >> 5, g = (k >> 3) & 3, jj = k & 7;
            int idx = ((s << 6) + (g << 4) + c) * 8 + jj;
            whl[idx] = h; wll[idx] = lo;
        }
        __syncthreads();
        frag8 whi[8], wlo[8];
#pragma unroll
        for (int s = 0; s < 8; ++s) {
            whi[s] = *(const frag8*)(whl + (s * 64 + lane) * 8);
            wlo[s] = *(const frag8*)(wll + (s * 64 + lane) * 8);
        }
        __syncthreads();  // W in regs; tiles may now reuse [0,32K)
        int col = lane & 15;
        int kg = lane >> 4;
        int v0 = bid * 128 + wvid * 16;
        char* myx = smem + wvid * 4096;
        f32x4 acc = {0.f, 0.f, 0.f, 0.f};
#pragma unroll
        for (int h = 0; h < 2; ++h) {
#pragma unroll
            for (int i = 0; i < 8; ++i) {
                int r = 2 * i + (lane >> 5);
                int row = min(v0 + r, N_NODES - 1);
                int c4 = lane & 31;
                float4 f = ((const float4*)(x + (size_t)row * F_IN + h * 128))[c4];
                short4 h4;
                h4.x = f32_bf16_native(f.x); h4.y = f32_bf16_native(f.y);
                h4.z = f32_bf16_native(f.z); h4.w = f32_bf16_native(f.w);
                int baddr = (r * 256 + c4 * 8) ^ ((r & 7) << 4);
                *(short4*)(myx + baddr) = h4;
            }
#pragma unroll
            for (int sp = 0; sp < 4; ++sp) {
                int s = h * 4 + sp;
                int baddr = (col * 256 + sp * 64 + kg * 16) ^ ((col & 7) << 4);
                frag8 a = *(const frag8*)(myx + baddr);
                acc = __builtin_amdgcn_mfma_f32_16x16x32_bf16(a, wlo[s], acc, 0, 0, 0);
                acc = __builtin_amdgcn_mfma_f32_16x16x32_bf16(a, whi[s], acc, 0, 0, 0);
            }
        }
#pragma unroll
        for (int r = 0; r < 4; ++r) {
            int gr = v0 + kg * 4 + r;
            if (gr < N_NODES) y1f[(size_t)gr * HID + col] = acc[r];
        }
    }
}

// ---------------- K2: per-bucket CSR build + y1 scale (uint4 temp reads) ---
__global__ __launch_bounds__(256) void build_kernel(const uint32_t* temp, const int* gcount,
                                                    int* row_start, float* dinv, int* ssort,
                                                    const float* __restrict__ y1f,
                                                    ushort* __restrict__ y1) {
    __shared__ int hist[256];
    __shared__ int cur[256];
    __shared__ int wsum[4];
    __shared__ int wsum2[4];
    __shared__ float dinvl[256];
    __shared__ int sbuf[BCAP];
    int b = blockIdx.x;
    int t = threadIdx.x;
    int lane = t & 63;
    int wvid = t >> 6;
    int g0 = (t < NBUCK && t < b) ? gcount[t] : 0;
    int g1 = (t + 256 < NBUCK && t + 256 < b) ? gcount[t + 256] : 0;
    int part = g0 + g1;
#pragma unroll
    for (int m = 1; m < 64; m <<= 1) part += __shfl_xor(part, m);
    if (lane == 0) wsum[wvid] = part;
    int cnt = min(gcount[b], BCAP);
    const uint32_t* tp = temp + (size_t)b * BCAP;
    const uint4* tp4 = (const uint4*)tp;
    int cnt4 = cnt >> 2;
    int tail0 = cnt4 << 2;
    hist[t] = 0;
    __syncthreads();
    int bs = wsum[0] + wsum[1] + wsum[2] + wsum[3];
    for (int i = t; i < cnt4; i += 256) {
        uint4 q = tp4[i];
        atomicAdd(&hist[q.x & 255], 1);
        atomicAdd(&hist[q.y & 255], 1);
        atomicAdd(&hist[q.z & 255], 1);
        atomicAdd(&hist[q.w & 255], 1);
    }
    for (int i = tail0 + t; i < cnt; i += 256) atomicAdd(&hist[tp[i] & 255], 1);
    __syncthreads();
    int dg = hist[t];
    int v = dg;
#pragma unroll
    for (int d = 1; d < 64; d <<= 1) {
        int up = __shfl_up(v, d);
        if (lane >= d) v += up;
    }
    if (lane == 63) wsum2[wvid] = v;
    __syncthreads();
    int pre = 0;
#pragma unroll
    for (int w = 0; w < 4; ++w) pre += (w < wvid) ? wsum2[w] : 0;
    int ex = pre + v - dg;
    int node = b * 256 + t;
    cur[t] = ex;
    float dvv = rsqrtf((float)(dg + 1));
    dinvl[t] = dvv;
    if (node < N_NODES) {
        row_start[node] = bs + ex;
        dinv[node] = dvv;
    }
    __syncthreads();
    for (int i = t; i < cnt4; i += 256) {
        uint4 q = tp4[i];
        int p0 = atomicAdd(&cur[q.x & 255], 1); sbuf[p0] = (int)(q.x >> 8);
        int p1 = atomicAdd(&cur[q.y & 255], 1); sbuf[p1] = (int)(q.y >> 8);
        int p2 = atomicAdd(&cur[q.z & 255], 1); sbuf[p2] = (int)(q.z >> 8);
        int p3 = atomicAdd(&cur[q.w & 255], 1); sbuf[p3] = (int)(q.w >> 8);
    }
    for (int i = tail0 + t; i < cnt; i += 256) {
        uint32_t vv = tp[i];
        int pos = atomicAdd(&cur[vv & 255], 1);
        sbuf[pos] = (int)(vv >> 8);
    }
    __syncthreads();
    for (int i = t; i < cnt; i += 256) ssort[bs + i] = sbuf[i];
    int n0 = b * 256;
    int nv = min(256, N_NODES - n0);
    int c4 = nv * 4;
    const float4* yin = (const float4*)(y1f + (size_t)n0 * HID);
    ushort4* yout = (ushort4*)(y1 + (size_t)n0 * HID);
    for (int i = t; i < c4; i += 256) {
        float4 f = yin[i];
        float d = dinvl[i >> 2];
        ushort4 o;
        o.x = (ushort)f32_bf16_native(f.x * d);
        o.y = (ushort)f32_bf16_native(f.y * d);
        o.z = (ushort)f32_bf16_native(f.z * d);
        o.w = (ushort)f32_bf16_native(f.w * d);
        yout[i] = o;
    }
    if (b == 0 && t == 0) row_start[N_NODES] = N_EDGES;
}

// ---- 2-node-per-wave gather+reduce, 32 edges/iter (deep MLP) ---------------
__device__ inline float4 gather_reduce32(const ushort* __restrict__ y,
                                         const int* __restrict__ row_start,
                                         const int* __restrict__ ssort,
                                         int v, int q, int eg) {
    int start = row_start[v];
    int end = row_start[v + 1];
    float4 acc = make_float4(0.f, 0.f, 0.f, 0.f);
    int base = start;
    // 32 edges/iter: 2 int2 ssort slots -> 4 independent y gathers in flight
    for (; base + 32 <= end; base += 32) {
        int2 ssA = *((const int2*)(ssort + base + 2 * eg));
        int2 ssB = *((const int2*)(ssort + base + 16 + 2 * eg));
        ushort4 y0 = *((const ushort4*)(y + (size_t)ssA.x * HID + q * 4));
        ushort4 y1 = *((const ushort4*)(y + (size_t)ssA.y * HID + q * 4));
        ushort4 y2 = *((const ushort4*)(y + (size_t)ssB.x * HID + q * 4));
        ushort4 y3 = *((const ushort4*)(y + (size_t)ssB.y * HID + q * 4));
        acc.x += (bf16_to_f32((short)y0.x) + bf16_to_f32((short)y1.x))
               + (bf16_to_f32((short)y2.x) + bf16_to_f32((short)y3.x));
        acc.y += (bf16_to_f32((short)y0.y) + bf16_to_f32((short)y1.y))
               + (bf16_to_f32((short)y2.y) + bf16_to_f32((short)y3.y));
        acc.z += (bf16_to_f32((short)y0.z) + bf16_to_f32((short)y1.z))
               + (bf16_to_f32((short)y2.z) + bf16_to_f32((short)y3.z));
        acc.w += (bf16_to_f32((short)y0.w) + bf16_to_f32((short)y1.w))
               + (bf16_to_f32((short)y2.w) + bf16_to_f32((short)y3.w));
    }
    for (; base + 16 <= end; base += 16) {
        int2 ss = *((const int2*)(ssort + base + 2 * eg));
        ushort4 y0 = *((const ushort4*)(y + (size_t)ss.x * HID + q * 4));
        ushort4 y1 = *((const ushort4*)(y + (size_t)ss.y * HID + q * 4));
        acc.x += bf16_to_f32((short)y0.x) + bf16_to_f32((short)y1.x);
        acc.y += bf16_to_f32((short)y0.y) + bf16_to_f32((short)y1.y);
        acc.z += bf16_to_f32((short)y0.z) + bf16_to_f32((short)y1.z);
        acc.w += bf16_to_f32((short)y0.w) + bf16_to_f32((short)y1.w);
    }
    for (; base < end; base += 8) {
        int e = base + eg;
        if (e < end) {
            int s = ssort[e];
            ushort4 yv = *((const ushort4*)(y + (size_t)s * HID + q * 4));
            acc.x += bf16_to_f32((short)yv.x);
            acc.y += bf16_to_f32((short)yv.y);
            acc.z += bf16_to_f32((short)yv.z);
            acc.w += bf16_to_f32((short)yv.w);
        }
    }
#pragma unroll
    for (int m = 1; m < 8; m <<= 1) {
        acc.x += __shfl_xor(acc.x, m);
        acc.y += __shfl_xor(acc.y, m);
        acc.z += __shfl_xor(acc.z, m);
        acc.w += __shfl_xor(acc.w, m);
    }
    return acc;
}

// ---------------- agg layer 1 fused with gemm2 (2 nodes/wave) --------------
__global__ __launch_bounds__(256) void aggA_kernel(const ushort* __restrict__ y,
                                                   const float* __restrict__ dinvp,
                                                   const float* __restrict__ b1,
                                                   const float* __restrict__ W2,
                                                   const int* __restrict__ row_start,
                                                   const int* __restrict__ ssort,
                                                   ushort* __restrict__ y2) {
    int wid = (blockIdx.x * blockDim.x + threadIdx.x) >> 6;
    int lane = threadIdx.x & 63;
    int g = lane >> 5;
    int idx = lane & 31;
    int q = idx >> 3;
    int eg = idx & 7;
    int v = 2 * wid + g;
    if (v >= N_NODES) return;
    // hoist independent loads so they overlap the gather chain
    ushort4 sv = *((const ushort4*)(y + (size_t)v * HID + q * 4));
    float dv = dinvp[v];
    float4 bv = *((const float4*)(b1 + q * 4));
    float4 acc = gather_reduce32(y, row_start, ssort, v, q, eg);
    float4 r;
    r.x = fmaxf(dv * (acc.x + bf16_to_f32((short)sv.x)) + bv.x, 0.f);
    r.y = fmaxf(dv * (acc.y + bf16_to_f32((short)sv.y)) + bv.y, 0.f);
    r.z = fmaxf(dv * (acc.z + bf16_to_f32((short)sv.z)) + bv.z, 0.f);
    r.w = fmaxf(dv * (acc.w + bf16_to_f32((short)sv.w)) + bv.w, 0.f);
    int row0 = q * 4;
#pragma unroll
    for (int p = 0; p < 2; ++p) {
        int c = eg + 8 * p;
        float partial = r.x * W2[(row0 + 0) * 16 + c]
                      + r.y * W2[(row0 + 1) * 16 + c]
                      + r.z * W2[(row0 + 2) * 16 + c]
                      + r.w * W2[(row0 + 3) * 16 + c];
        partial += __shfl_xor(partial, 8);
        partial += __shfl_xor(partial, 16);
        if (q == 0) y2[(size_t)v * HID + c] = (ushort)f32_bf16_native(dv * partial);
    }
}

// ---------------- agg layer 2 fused with output + log_softmax --------------
__global__ __launch_bounds__(256) void aggB_kernel(const ushort* __restrict__ y,
                                                   const float* __restrict__ dinvp,
                                                   const float* __restrict__ b2,
                                                   const float* __restrict__ Wout,
                                                   const float* __restrict__ bout,
                                                   const int* __restrict__ row_start,
                                                   const int* __restrict__ ssort,
                                                   float* __restrict__ out) {
    int wid = (blockIdx.x * blockDim.x + threadIdx.x) >> 6;
    int lane = threadIdx.x & 63;
    int g = lane >> 5;
    int idx = lane & 31;
    int q = idx >> 3;
    int eg = idx & 7;
    int v = 2 * wid + g;
    if (v >= N_NODES) return;
    ushort4 sv = *((const ushort4*)(y + (size_t)v * HID + q * 4));
    float dv = dinvp[v];
    float4 bv = *((const float4*)(b2 + q * 4));
    float4 acc = gather_reduce32(y, row_start, ssort, v, q, eg);
    float4 r;
    r.x = fmaxf(dv * (acc.x + bf16_to_f32((short)sv.x)) + bv.x, 0.f);
    r.y = fmaxf(dv * (acc.y + bf16_to_f32((short)sv.y)) + bv.y, 0.f);
    r.z = fmaxf(dv * (acc.z + bf16_to_f32((short)sv.z)) + bv.z, 0.f);
    r.w = fmaxf(dv * (acc.w + bf16_to_f32((short)sv.w)) + bv.w, 0.f);
    int row0 = q * 4;
    int c = eg;
    float partial = 0.f;
    if (c < NCLS) {
        partial = r.x * Wout[(row0 + 0) * NCLS + c]
                + r.y * Wout[(row0 + 1) * NCLS + c]
                + r.z * Wout[(row0 + 2) * NCLS + c]
                + r.w * Wout[(row0 + 3) * NCLS + c];
    }
    partial += __shfl_xor(partial, 8);
    partial += __shfl_xor(partial, 16);
    float lg = (c < NCLS) ? (partial + bout[c]) : -1e30f;
    float mx = lg;
#pragma unroll
    for (int m = 1; m < 8; m <<= 1) mx = fmaxf(mx, __shfl_xor(mx, m));
    float e = (c < NCLS) ? expf(lg - mx) : 0.f;
    float ssum = e;
#pragma unroll
    for (int m = 1; m < 8; m <<= 1) ssum += __shfl_xor(ssum, m);
    if (q == 0 && c < NCLS) {
        float lse = mx + logf(ssum);
        out[(size_t)v * NCLS + c] = lg - lse;
    }
}

extern "C" void kernel_launch(void* const* d_in, const int* in_sizes, int n_in,
                              void* d_out, int out_size, void* d_ws, size_t ws_size,
                              hipStream_t stream) {
    const float* x    = (const float*)d_in[0];
    const void*  edge = d_in[1];
    const float* W1   = (const float*)d_in[2];
    const float* b1   = (const float*)d_in[3];
    const float* W2   = (const float*)d_in[4];
    const float* b2   = (const float*)d_in[5];
    const float* Wout = (const float*)d_in[6];
    const float* bout = (const float*)d_in[7];
    float* out = (float*)d_out;
    char* ws = (char*)d_ws;

    auto al = [](size_t v) { return (v + 255) & ~(size_t)255; };
    size_t o = 0;
    int*      gcount    = (int*)(ws + o);      o = al(o + (size_t)NBUCK * 4);
    int*      row_start = (int*)(ws + o);      o = al(o + (size_t)(N_NODES + 1) * 4);
    float*    dinv      = (float*)(ws + o);    o = al(o + (size_t)N_NODES * 4);
    uint32_t* temp      = (uint32_t*)(ws + o); o = al(o + (size_t)NBUCK * BCAP * 4);
    int*      ssort     = (int*)(ws + o);      o = al(o + (size_t)N_EDGES * 4);
    float*    y1fbuf    = (float*)(ws + o);    o = al(o + (size_t)N_NODES * HID * 4);
    ushort*   y1buf     = (ushort*)(ws + o);   o = al(o + (size_t)N_NODES * HID * 2);
    ushort*   y2buf     = (ushort*)(ws + o);   o = al(o + (size_t)N_NODES * HID * 2);

    hipMemsetAsync(gcount, 0, (size_t)NBUCK * 4, stream);
    k1_kernel<<<2 * NBLK, 512, 0, stream>>>(edge, gcount, temp, x, W1, y1fbuf);
    build_kernel<<<NBUCK, 256, 0, stream>>>(temp, gcount, row_start, dinv, ssort, y1fbuf, y1buf);
    aggA_kernel<<<12500, 256, 0, stream>>>(y1buf, dinv, b1, W2, row_start, ssort, y2buf);
    aggB_kernel<<<12500, 256, 0, stream>>>(y2buf, dinv, b2, Wout, bout, row_start, ssort, out);
}

// Round 22
// 121.868 us; speedup vs baseline: 1.0584x; 1.0584x over previous
//
#include <hip/hip_runtime.h>
#include <hip/hip_bf16.h>
#include <stdint.h>

#define N_NODES 100000
#define N_EDGES 3200000
#define F_IN 256
#define HID 16
#define NCLS 7

#define NBUCK 391        // ceil(100000 / 256) buckets of 256 nodes (dst >> 8)
#define BCAP 9216        // capacity per bucket (avg 8184 -> ample headroom)
#define EPB 4096         // edges per bucket-block (8 per thread @512)
#define NBLK ((N_EDGES + EPB - 1) / EPB)              // 782

using frag8 = __attribute__((ext_vector_type(8))) short;
using f32x4 = __attribute__((ext_vector_type(4))) float;

__device__ inline short f32_to_bf16_rn(float f) {
    uint32_t u = __float_as_uint(f);
    uint32_t r = (u + 0x7FFF + ((u >> 16) & 1)) >> 16;
    return (short)r;
}
__device__ inline float bf16_to_f32(short s) {
    return __uint_as_float(((uint32_t)(uint16_t)s) << 16);
}
__device__ inline short f32_bf16_native(float f) {
    __hip_bfloat16 h = __float2bfloat16(f);
    union { __hip_bfloat16 b; unsigned short u; } cv;
    cv.b = h;
    return (short)cv.u;
}

// ---------------- K1: ROLE-INTERLEAVED bucket ∥ GEMM blocks (r20 form) -----
__global__ __launch_bounds__(512) void k1_kernel(const void* edge_raw,
                                                 int* gcount, uint32_t* temp,
                                                 const float* __restrict__ x,
                                                 const float* __restrict__ W1,
                                                 float* __restrict__ y1f) {
    __shared__ __align__(16) char smem[32768];
    int t = threadIdx.x;
    int lane = t & 63;
    int wvid = t >> 6;
    int role = blockIdx.x & 1;
    int bid = blockIdx.x >> 1;
    if (role == 0) {
        uint32_t* buf2      = (uint32_t*)smem;            // 16384 B
        uint16_t* bucket_of = (uint16_t*)(smem + 16384);  //  8192 B
        int* cnt   = (int*)(smem + 24576);                //  1564 B
        int* lofs  = (int*)(smem + 26140);                //  1568 B
        int* gbase = (int*)(smem + 27708);                //  1564 B
        int* wsum  = (int*)(smem + 29272);                //    32 B
        int* s_is32 = (int*)(smem + 29304);               //     4 B
        if (t == 0) *s_is32 = 0;
        if (t < NBUCK) cnt[t] = 0;
        __syncthreads();
        uint32_t probe = ((const uint32_t*)edge_raw)[2 * t + 1];
        if (probe) atomicOr(s_is32, 1);
        __syncthreads();
        int is64 = (*s_is32 == 0);
        int e0 = bid * EPB;
        int total = min(EPB, N_EDGES - e0);
        int sv[8], dvv[8];
        if (is64) {
            const long long* pS = (const long long*)edge_raw + e0;
            const long long* pD = (const long long*)edge_raw + N_EDGES + e0;
            ulonglong2 sp[4], dp[4];
#pragma unroll
            for (int k = 0; k < 4; ++k) {
                int be = e0 + k * 1024 + 2 * t;
                if (be + 1 < N_EDGES) {
                    sp[k] = ((const ulonglong2*)(pS + k * 1024))[t];
                    dp[k] = ((const ulonglong2*)(pD + k * 1024))[t];
                } else {
                    sp[k].x = (be < N_EDGES) ? (unsigned long long)pS[k * 1024 + 2 * t] : ~0ull;
                    sp[k].y = ~0ull;
                    dp[k].x = (be < N_EDGES) ? (unsigned long long)pD[k * 1024 + 2 * t] : ~0ull;
                    dp[k].y = ~0ull;
                }
            }
#pragma unroll
            for (int k = 0; k < 4; ++k) {
                int be = e0 + k * 1024 + 2 * t;
                sv[2 * k]      = (be < N_EDGES) ? (int)sp[k].x : -1;
                dvv[2 * k]     = (be < N_EDGES) ? (int)dp[k].x : -1;
                sv[2 * k + 1]  = (be + 1 < N_EDGES) ? (int)sp[k].y : -1;
                dvv[2 * k + 1] = (be + 1 < N_EDGES) ? (int)dp[k].y : -1;
            }
        } else {
            const int* pS = (const int*)edge_raw + e0;
            const int* pD = (const int*)edge_raw + N_EDGES + e0;
            int4 sq[2], dq[2];
#pragma unroll
            for (int k = 0; k < 2; ++k) {
                int be = e0 + k * 2048 + 4 * t;
                if (be + 3 < N_EDGES) {
                    sq[k] = ((const int4*)(pS + k * 2048))[t];
                    dq[k] = ((const int4*)(pD + k * 2048))[t];
                } else {
                    int* s4 = (int*)&sq[k]; int* d4 = (int*)&dq[k];
#pragma unroll
                    for (int j = 0; j < 4; ++j) {
                        int e = be + j;
                        s4[j] = (e < N_EDGES) ? pS[k * 2048 + 4 * t + j] : -1;
                        d4[j] = (e < N_EDGES) ? pD[k * 2048 + 4 * t + j] : -1;
                    }
                }
            }
#pragma unroll
            for (int k = 0; k < 2; ++k) {
                int be = e0 + k * 2048 + 4 * t;
                const int* s4 = (const int*)&sq[k];
                const int* d4 = (const int*)&dq[k];
#pragma unroll
                for (int j = 0; j < 4; ++j) {
                    int slot = 4 * k + j;
                    int ok = (be + j < N_EDGES);
                    sv[slot] = ok ? s4[j] : -1;
                    dvv[slot] = ok ? d4[j] : -1;
                }
            }
        }
        uint32_t val[8];
        int bk[8], rk[8];
#pragma unroll
        for (int k = 0; k < 8; ++k) {
            if (dvv[k] >= 0) {
                int b = dvv[k] >> 8;
                val[k] = ((uint32_t)sv[k] << 8) | (uint32_t)(dvv[k] & 255);
                bk[k] = b;
                rk[k] = atomicAdd(&cnt[b], 1);
            } else {
                bk[k] = -1;
            }
        }
        __syncthreads();
        int cv = (t < NBUCK) ? cnt[t] : 0;
        int v = cv;
#pragma unroll
        for (int d = 1; d < 64; d <<= 1) {
            int up = __shfl_up(v, d);
            if (lane >= d) v += up;
        }
        if (lane == 63) wsum[wvid] = v;
        __syncthreads();
        int pre = 0;
#pragma unroll
        for (int w = 0; w < 8; ++w) pre += (w < wvid) ? wsum[w] : 0;
        if (t < NBUCK) lofs[t] = pre + v - cv;
        __syncthreads();
#pragma unroll
        for (int k = 0; k < 8; ++k) {
            if (bk[k] >= 0) {
                int p = lofs[bk[k]] + rk[k];
                buf2[p] = val[k];
                bucket_of[p] = (uint16_t)bk[k];
            }
        }
        if (t < NBUCK) {
            int c = cnt[t];
            gbase[t] = c ? atomicAdd(&gcount[t], c) : 0;
        }
        __syncthreads();
        for (int i = t; i < total; i += 512) {
            int b = bucket_of[i];
            int pos = gbase[b] + (i - lofs[b]);
            if (pos < BCAP) temp[(size_t)b * BCAP + pos] = buf2[i];
        }
    } else {
        short* whl = (short*)smem;            // 8192 B
        short* wll = (short*)(smem + 8192);   // 8192 B
#pragma unroll
        for (int j = 0; j < 8; ++j) {
            int wdx = t * 8 + j;
            float wvv = W1[wdx];
            short h = f32_to_bf16_rn(wvv);
            short lo = f32_to_bf16_rn(wvv - bf16_to_f32(h));
            int k = wdx >> 4, c = wdx & 15;
            int s = k >> 5, g = (k >> 3) & 3, jj = k & 7;
            int idx = ((s << 6) + (g << 4) + c) * 8 + jj;
            whl[idx] = h; wll[idx] = lo;
        }
        __syncthreads();
        frag8 whi[8], wlo[8];
#pragma unroll
        for (int s = 0; s < 8; ++s) {
            whi[s] = *(const frag8*)(whl + (s * 64 + lane) * 8);
            wlo[s] = *(const frag8*)(wll + (s * 64 + lane) * 8);
        }
        __syncthreads();  // W in regs; tiles may now reuse [0,32K)
        int col = lane & 15;
        int kg = lane >> 4;
        int v0 = bid * 128 + wvid * 16;
        char* myx = smem + wvid * 4096;
        f32x4 acc = {0.f, 0.f, 0.f, 0.f};
#pragma unroll
        for (int h = 0; h < 2; ++h) {
#pragma unroll
            for (int i = 0; i < 8; ++i) {
                int r = 2 * i + (lane >> 5);
                int row = min(v0 + r, N_NODES - 1);
                int c4 = lane & 31;
                float4 f = ((const float4*)(x + (size_t)row * F_IN + h * 128))[c4];
                short4 h4;
                h4.x = f32_bf16_native(f.x); h4.y = f32_bf16_native(f.y);
                h4.z = f32_bf16_native(f.z); h4.w = f32_bf16_native(f.w);
                int baddr = (r * 256 + c4 * 8) ^ ((r & 7) << 4);
                *(short4*)(myx + baddr) = h4;
            }
#pragma unroll
            for (int sp = 0; sp < 4; ++sp) {
                int s = h * 4 + sp;
                int baddr = (col * 256 + sp * 64 + kg * 16) ^ ((col & 7) << 4);
                frag8 a = *(const frag8*)(myx + baddr);
                acc = __builtin_amdgcn_mfma_f32_16x16x32_bf16(a, wlo[s], acc, 0, 0, 0);
                acc = __builtin_amdgcn_mfma_f32_16x16x32_bf16(a, whi[s], acc, 0, 0, 0);
            }
        }
#pragma unroll
        for (int r = 0; r < 4; ++r) {
            int gr = v0 + kg * 4 + r;
            if (gr < N_NODES) y1f[(size_t)gr * HID + col] = acc[r];
        }
    }
}

// ---------------- K2: per-bucket CSR build + y1 scale (uint4 temp reads) ---
__global__ __launch_bounds__(256) void build_kernel(const uint32_t* temp, const int* gcount,
                                                    int* row_start, float* dinv, int* ssort,
                                                    const float* __restrict__ y1f,
                                                    ushort* __restrict__ y1) {
    __shared__ int hist[256];
    __shared__ int cur[256];
    __shared__ int wsum[4];
    __shared__ int wsum2[4];
    __shared__ float dinvl[256];
    __shared__ int sbuf[BCAP];
    int b = blockIdx.x;
    int t = threadIdx.x;
    int lane = t & 63;
    int wvid = t >> 6;
    int g0 = (t < NBUCK && t < b) ? gcount[t] : 0;
    int g1 = (t + 256 < NBUCK && t + 256 < b) ? gcount[t + 256] : 0;
    int part = g0 + g1;
#pragma unroll
    for (int m = 1; m < 64; m <<= 1) part += __shfl_xor(part, m);
    if (lane == 0) wsum[wvid] = part;
    int cnt = min(gcount[b], BCAP);
    const uint32_t* tp = temp + (size_t)b * BCAP;
    const uint4* tp4 = (const uint4*)tp;
    int cnt4 = cnt >> 2;
    int tail0 = cnt4 << 2;
    hist[t] = 0;
    __syncthreads();
    int bs = wsum[0] + wsum[1] + wsum[2] + wsum[3];
    for (int i = t; i < cnt4; i += 256) {
        uint4 q = tp4[i];
        atomicAdd(&hist[q.x & 255], 1);
        atomicAdd(&hist[q.y & 255], 1);
        atomicAdd(&hist[q.z & 255], 1);
        atomicAdd(&hist[q.w & 255], 1);
    }
    for (int i = tail0 + t; i < cnt; i += 256) atomicAdd(&hist[tp[i] & 255], 1);
    __syncthreads();
    int dg = hist[t];
    int v = dg;
#pragma unroll
    for (int d = 1; d < 64; d <<= 1) {
        int up = __shfl_up(v, d);
        if (lane >= d) v += up;
    }
    if (lane == 63) wsum2[wvid] = v;
    __syncthreads();
    int pre = 0;
#pragma unroll
    for (int w = 0; w < 4; ++w) pre += (w < wvid) ? wsum2[w] : 0;
    int ex = pre + v - dg;
    int node = b * 256 + t;
    cur[t] = ex;
    float dvv = rsqrtf((float)(dg + 1));
    dinvl[t] = dvv;
    if (node < N_NODES) {
        row_start[node] = bs + ex;
        dinv[node] = dvv;
    }
    __syncthreads();
    for (int i = t; i < cnt4; i += 256) {
        uint4 q = tp4[i];
        int p0 = atomicAdd(&cur[q.x & 255], 1); sbuf[p0] = (int)(q.x >> 8);
        int p1 = atomicAdd(&cur[q.y & 255], 1); sbuf[p1] = (int)(q.y >> 8);
        int p2 = atomicAdd(&cur[q.z & 255], 1); sbuf[p2] = (int)(q.z >> 8);
        int p3 = atomicAdd(&cur[q.w & 255], 1); sbuf[p3] = (int)(q.w >> 8);
    }
    for (int i = tail0 + t; i < cnt; i += 256) {
        uint32_t vv = tp[i];
        int pos = atomicAdd(&cur[vv & 255], 1);
        sbuf[pos] = (int)(vv >> 8);
    }
    __syncthreads();
    for (int i = t; i < cnt; i += 256) ssort[bs + i] = sbuf[i];
    int n0 = b * 256;
    int nv = min(256, N_NODES - n0);
    int c4n = nv * 4;
    const float4* yin = (const float4*)(y1f + (size_t)n0 * HID);
    ushort4* yout = (ushort4*)(y1 + (size_t)n0 * HID);
    for (int i = t; i < c4n; i += 256) {
        float4 f = yin[i];
        float d = dinvl[i >> 2];
        ushort4 o;
        o.x = (ushort)f32_bf16_native(f.x * d);
        o.y = (ushort)f32_bf16_native(f.y * d);
        o.z = (ushort)f32_bf16_native(f.z * d);
        o.w = (ushort)f32_bf16_native(f.w * d);
        yout[i] = o;
    }
    if (b == 0 && t == 0) row_start[N_NODES] = N_EDGES;
}

// ---- half-row gather: lane = g*32 + eg*2 + h; 16B y-loads (2 req/edge) ----
__device__ inline void acc8(uint4 u, float* a) {
    a[0] += __uint_as_float(u.x << 16);
    a[1] += __uint_as_float(u.x & 0xFFFF0000u);
    a[2] += __uint_as_float(u.y << 16);
    a[3] += __uint_as_float(u.y & 0xFFFF0000u);
    a[4] += __uint_as_float(u.z << 16);
    a[5] += __uint_as_float(u.z & 0xFFFF0000u);
    a[6] += __uint_as_float(u.w << 16);
    a[7] += __uint_as_float(u.w & 0xFFFF0000u);
}

__device__ inline void gather_half(const ushort* __restrict__ y,
                                   const int* __restrict__ row_start,
                                   const int* __restrict__ ssort,
                                   int v, int h, int eg, float* a) {
    int start = row_start[v];
    int end = row_start[v + 1];
    int base = start;
    // 32 edges/iter: int2 ssort per eg-slot, 2 independent 16B y-loads in flight
    for (; base + 32 <= end; base += 32) {
        int2 ss = *((const int2*)(ssort + base + 2 * eg));
        uint4 u0 = *((const uint4*)(y + (size_t)ss.x * HID + h * 8));
        uint4 u1 = *((const uint4*)(y + (size_t)ss.y * HID + h * 8));
        acc8(u0, a);
        acc8(u1, a);
    }
    // 16-edge chunk: scalar ssort (one cache line), 1 y-load per lane
    for (; base + 16 <= end; base += 16) {
        int s = ssort[base + eg];
        uint4 u = *((const uint4*)(y + (size_t)s * HID + h * 8));
        acc8(u, a);
    }
    // masked tail (<16 edges)
    if (base < end) {
        int e = base + eg;
        if (e < end) {
            int s = ssort[e];
            uint4 u = *((const uint4*)(y + (size_t)s * HID + h * 8));
            acc8(u, a);
        }
    }
    // reduce across the 16 eg slots (lane bits 1..4)
#pragma unroll
    for (int m = 2; m <= 16; m <<= 1) {
        a[0] += __shfl_xor(a[0], m);
        a[1] += __shfl_xor(a[1], m);
        a[2] += __shfl_xor(a[2], m);
        a[3] += __shfl_xor(a[3], m);
        a[4] += __shfl_xor(a[4], m);
        a[5] += __shfl_xor(a[5], m);
        a[6] += __shfl_xor(a[6], m);
        a[7] += __shfl_xor(a[7], m);
    }
}

// ---------------- agg layer 1 fused with gemm2 (2 nodes/wave) --------------
__global__ __launch_bounds__(256) void aggA_kernel(const ushort* __restrict__ y,
                                                   const float* __restrict__ dinvp,
                                                   const float* __restrict__ b1,
                                                   const float* __restrict__ W2,
                                                   const int* __restrict__ row_start,
                                                   const int* __restrict__ ssort,
                                                   ushort* __restrict__ y2) {
    int wid = (blockIdx.x * blockDim.x + threadIdx.x) >> 6;
    int lane = threadIdx.x & 63;
    int g = lane >> 5;
    int idx = lane & 31;
    int h = idx & 1;
    int eg = idx >> 1;
    int v = 2 * wid + g;
    if (v >= N_NODES) return;
    // hoisted independent loads
    uint4 su = *((const uint4*)(y + (size_t)v * HID + h * 8));
    float dv = dinvp[v];
    float4 bv0 = *((const float4*)(b1 + h * 8));
    float4 bv1 = *((const float4*)(b1 + h * 8 + 4));
    float a[8] = {0.f, 0.f, 0.f, 0.f, 0.f, 0.f, 0.f, 0.f};
    gather_half(y, row_start, ssort, v, h, eg, a);
    float self[8];
    self[0] = __uint_as_float(su.x << 16); self[1] = __uint_as_float(su.x & 0xFFFF0000u);
    self[2] = __uint_as_float(su.y << 16); self[3] = __uint_as_float(su.y & 0xFFFF0000u);
    self[4] = __uint_as_float(su.z << 16); self[5] = __uint_as_float(su.z & 0xFFFF0000u);
    self[6] = __uint_as_float(su.w << 16); self[7] = __uint_as_float(su.w & 0xFFFF0000u);
    float bb[8] = {bv0.x, bv0.y, bv0.z, bv0.w, bv1.x, bv1.y, bv1.z, bv1.w};
    float r[8];
#pragma unroll
    for (int j = 0; j < 8; ++j) r[j] = fmaxf(dv * (a[j] + self[j]) + bb[j], 0.f);
    // matvec: output col c = eg; rows h*8..h*8+7 partial, combine h via xor(1)
    int c = eg;
    float partial = 0.f;
#pragma unroll
    for (int j = 0; j < 8; ++j) partial += r[j] * W2[(h * 8 + j) * 16 + c];
    partial += __shfl_xor(partial, 1);
    if (h == 0) y2[(size_t)v * HID + c] = (ushort)f32_bf16_native(dv * partial);
}

// ---------------- agg layer 2 fused with output + log_softmax --------------
__global__ __launch_bounds__(256) void aggB_kernel(const ushort* __restrict__ y,
                                                   const float* __restrict__ dinvp,
                                                   const float* __restrict__ b2,
                                                   const float* __restrict__ Wout,
                                                   const float* __restrict__ bout,
                                                   const int* __restrict__ row_start,
                                                   const int* __restrict__ ssort,
                                                   float* __restrict__ out) {
    int wid = (blockIdx.x * blockDim.x + threadIdx.x) >> 6;
    int lane = threadIdx.x & 63;
    int g = lane >> 5;
    int idx = lane & 31;
    int h = idx & 1;
    int eg = idx >> 1;
    int v = 2 * wid + g;
    if (v >= N_NODES) return;
    uint4 su = *((const uint4*)(y + (size_t)v * HID + h * 8));
    float dv = dinvp[v];
    float4 bv0 = *((const float4*)(b2 + h * 8));
    float4 bv1 = *((const float4*)(b2 + h * 8 + 4));
    float a[8] = {0.f, 0.f, 0.f, 0.f, 0.f, 0.f, 0.f, 0.f};
    gather_half(y, row_start, ssort, v, h, eg, a);
    float self[8];
    self[0] = __uint_as_float(su.x << 16); self[1] = __uint_as_float(su.x & 0xFFFF0000u);
    self[2] = __uint_as_float(su.y << 16); self[3] = __uint_as_float(su.y & 0xFFFF0000u);
    self[4] = __uint_as_float(su.z << 16); self[5] = __uint_as_float(su.z & 0xFFFF0000u);
    self[6] = __uint_as_float(su.w << 16); self[7] = __uint_as_float(su.w & 0xFFFF0000u);
    float bb[8] = {bv0.x, bv0.y, bv0.z, bv0.w, bv1.x, bv1.y, bv1.z, bv1.w};
    float r[8];
#pragma unroll
    for (int j = 0; j < 8; ++j) r[j] = fmaxf(dv * (a[j] + self[j]) + bb[j], 0.f);
    int c = eg;
    float partial = 0.f;
    if (c < NCLS) {
#pragma unroll
        for (int j = 0; j < 8; ++j) partial += r[j] * Wout[(h * 8 + j) * NCLS + c];
    }
    partial += __shfl_xor(partial, 1);
    float lg = (c < NCLS) ? (partial + bout[c]) : -1e30f;
    float mx = lg;
#pragma unroll
    for (int m = 2; m <= 16; m <<= 1) mx = fmaxf(mx, __shfl_xor(mx, m));
    float e = (c < NCLS) ? expf(lg - mx) : 0.f;
    float ssum = e;
#pragma unroll
    for (int m = 2; m <= 16; m <<= 1) ssum += __shfl_xor(ssum, m);
    if (h == 0 && c < NCLS) {
        float lse = mx + logf(ssum);
        out[(size_t)v * NCLS + c] = lg - lse;
    }
}

extern "C" void kernel_launch(void* const* d_in, const int* in_sizes, int n_in,
                              void* d_out, int out_size, void* d_ws, size_t ws_size,
                              hipStream_t stream) {
    const float* x    = (const float*)d_in[0];
    const void*  edge = d_in[1];
    const float* W1   = (const float*)d_in[2];
    const float* b1   = (const float*)d_in[3];
    const float* W2   = (const float*)d_in[4];
    const float* b2   = (const float*)d_in[5];
    const float* Wout = (const float*)d_in[6];
    const float* bout = (const float*)d_in[7];
    float* out = (float*)d_out;
    char* ws = (char*)d_ws;

    auto al = [](size_t v) { return (v + 255) & ~(size_t)255; };
    size_t o = 0;
    int*      gcount    = (int*)(ws + o);      o = al(o + (size_t)NBUCK * 4);
    int*      row_start = (int*)(ws + o);      o = al(o + (size_t)(N_NODES + 1) * 4);
    float*    dinv      = (float*)(ws + o);    o = al(o + (size_t)N_NODES * 4);
    uint32_t* temp      = (uint32_t*)(ws + o); o = al(o + (size_t)NBUCK * BCAP * 4);
    int*      ssort     = (int*)(ws + o);      o = al(o + (size_t)N_EDGES * 4);
    float*    y1fbuf    = (float*)(ws + o);    o = al(o + (size_t)N_NODES * HID * 4);
    ushort*   y1buf     = (ushort*)(ws + o);   o = al(o + (size_t)N_NODES * HID * 2);
    ushort*   y2buf     = (ushort*)(ws + o);   o = al(o + (size_t)N_NODES * HID * 2);

    hipMemsetAsync(gcount, 0, (size_t)NBUCK * 4, stream);
    k1_kernel<<<2 * NBLK, 512, 0, stream>>>(edge, gcount, temp, x, W1, y1fbuf);
    build_kernel<<<NBUCK, 256, 0, stream>>>(temp, gcount, row_start, dinv, ssort, y1fbuf, y1buf);
    aggA_kernel<<<12500, 256, 0, stream>>>(y1buf, dinv, b1, W2, row_start, ssort, y2buf);
    aggB_kernel<<<12500, 256, 0, stream>>>(y2buf, dinv, b2, Wout, bout, row_start, ssort, out);
}